// Round 8
// baseline (27.700 us; speedup 1.0000x reference)
//
#include <hip/hip_runtime.h>
#include <math.h>

// Reranker tie-aware RankNet loss — R8.
// Single compute kernel + tiny (16 B) memset node that zeroes {f32 sum, u64
// packed counter} in d_ws every replay (also fixes poison/first-call, leaves
// no cross-call state).
// B=4096 rows, n=64. 512 blocks x 256 thr; each 64-lane wave does 2 rows.
//   - group-end e via one __ballot + ctz;  mask (b > e);  cnt analytic
//   - softplus base-2 log-of-product: ONE v_exp_f32 per pair, one v_log per lane
//     (8 chains x up to 16 factors in (1,2] -> <= 2^16, no overflow)
// Grid reduction via RELAXED agent-scope HW atomics (no acq_rel -> no L2
// writeback storms): per block one f32 atomicAdd (sum), one explicit
// s_waitcnt vmcnt(0) to order it, one u64 atomicAdd of (1<<32)|count.
// The block whose counter RMW returns hi==nb-1 is ordered after ALL sum-adds
// (each block's sum-add completed before its counter-add issued) -> it loads
// the final sum and writes out = S*ln2/C.

#define N 64
#define WPB 4                   // waves per 256-thread block
#define RPW 2                   // rows per wave
#define LN2 0.6931471805599453f
#define LOG2E 1.4426950408889634f

__device__ __forceinline__ float readlane_f(float v, int srclane) {
    return __int_as_float(__builtin_amdgcn_readlane(__float_as_int(v), srclane));
}

#define TERM(i, p, r) do {                                         \
    const int b_ = bb + (i);                                       \
    float t_  = readlane_f(pa2, b_) - pa2;                         \
    float g_  = __builtin_amdgcn_exp2f(-fabsf(t_));                \
    bool  m_  = b_ > e;                                            \
    float gm_ = m_ ? g_ : 0.0f;                                    \
    p = fmaf(gm_, p, p);              /* p *= (1 + masked g) */    \
    r += m_ ? fmaxf(t_, 0.0f) : 0.0f;                              \
} while (0)

__global__ __launch_bounds__(256) void rank_loss_fused(
    const float* __restrict__ logits, const int* __restrict__ kd,
    float* __restrict__ out, float* __restrict__ sumF,
    unsigned long long* __restrict__ cntPk, int B, int nb)
{
    const int lane = threadIdx.x & 63;
    const int wave = threadIdx.x >> 6;

    float p0=1.f,p1=1.f,p2=1.f,p3=1.f,p4=1.f,p5=1.f,p6=1.f,p7=1.f;
    float r0=0.f,r1=0.f,r2=0.f,r3=0.f,r4=0.f,r5=0.f,r6=0.f,r7=0.f;
    float cnt = 0.f;

    #pragma unroll
    for (int rr = 0; rr < RPW; ++rr) {
        const int row = (blockIdx.x * WPB + wave) * RPW + rr;
        if (row < B) {
            const int base = row * N + lane;
            const int   k   = kd[base];
            const float pa2 = logits[base] * LOG2E;

            // group-end lane e: smallest j >= lane with (j==63 or k[j]!=k[j+1])
            const int knext = __shfl_down(k, 1);
            unsigned long long endm = __ballot(lane == 63 || k != knext);
            const int e = lane + __builtin_ctzll(endm >> lane);   // bit 63 set
            cnt += (float)(63 - e);

            #pragma unroll 1
            for (int bb = 0; bb < N; bb += 8) {
                TERM(0, p0, r0); TERM(1, p1, r1); TERM(2, p2, r2); TERM(3, p3, r3);
                TERM(4, p4, r4); TERM(5, p5, r5); TERM(6, p6, r6); TERM(7, p7, r7);
            }
        }
    }

    float prod = ((p0 * p1) * (p2 * p3)) * ((p4 * p5) * (p6 * p7));
    float rsum = ((r0 + r1) + (r2 + r3)) + ((r4 + r5) + (r6 + r7));
    float psum = rsum + __builtin_amdgcn_logf(prod);   // v_log_f32 == log2

    #pragma unroll
    for (int off = 32; off; off >>= 1) {
        psum += __shfl_down(psum, off);
        cnt  += __shfl_down(cnt,  off);
    }

    __shared__ float ssum[WPB], scnt[WPB];
    if (lane == 0) { ssum[wave] = psum; scnt[wave] = cnt; }
    __syncthreads();

    if (threadIdx.x == 0) {
        float s = 0.f, c = 0.f;
        #pragma unroll
        for (int w = 0; w < WPB; ++w) { s += ssum[w]; c += scnt[w]; }

        // 1) accumulate sum (relaxed, agent scope -> coherent point, no wbL2)
        (void)__hip_atomic_fetch_add(sumF, s, __ATOMIC_RELAXED,
                                     __HIP_MEMORY_SCOPE_AGENT);
        // 2) order: sum-add must be performed before counter-add issues
        asm volatile("s_waitcnt vmcnt(0)" ::: "memory");
        // 3) packed counter: hi += 1 (arrival), lo += pair count (exact int)
        const unsigned cc = (unsigned)c;
        const unsigned long long pk = (1ull << 32) | (unsigned long long)cc;
        unsigned long long old = __hip_atomic_fetch_add(
            cntPk, pk, __ATOMIC_RELAXED, __HIP_MEMORY_SCOPE_AGENT);

        if ((unsigned)(old >> 32) == (unsigned)(nb - 1)) {
            // last arrival: every block's sum-add is performed (see header)
            float S = __hip_atomic_load(sumF, __ATOMIC_RELAXED,
                                        __HIP_MEMORY_SCOPE_AGENT);
            unsigned C = (unsigned)(old & 0xffffffffu) + cc;
            out[0] = S * LN2 / (float)C;
        }
    }
}

extern "C" void kernel_launch(void* const* d_in, const int* in_sizes, int n_in,
                              void* d_out, int out_size, void* d_ws, size_t ws_size,
                              hipStream_t stream) {
    const float* logits = (const float*)d_in[0];
    const int*   kd     = (const int*)d_in[1];
    float*       out    = (float*)d_out;
    const int B  = in_sizes[1] / N;                      // 4096
    const int nb = B / (WPB * RPW);                      // 512 blocks

    float*              sumF  = (float*)d_ws;            // ws[0:4)
    unsigned long long* cntPk = (unsigned long long*)((char*)d_ws + 8); // ws[8:16)

    // Zero the two accumulators every call (memset node in the graph):
    // fixes first-call poison and leaves no state across calls.
    hipMemsetAsync(d_ws, 0, 16, stream);
    rank_loss_fused<<<nb, 256, 0, stream>>>(logits, kd, out, sumF, cntPk, B, nb);
}

// Round 9
// 13.151 us; speedup vs baseline: 2.1063x; 2.1063x over previous
//
#include <hip/hip_runtime.h>
#include <math.h>

// Reranker tie-aware RankNet loss — R9 (single node, contention-free finalize).
// B=4096 rows, n=64. 512 blocks x 256 thr; each 64-lane wave does 2 rows.
//   - group-end e via one __ballot + ctz;  mask (b > e);  cnt analytic
//   - softplus base-2 log-of-product: ONE v_exp_f32 per pair; one v_log/lane
//     (8 chains x 16 factors in (1,2] -> <= 2^16, no overflow)
// Grid finalize WITHOUT same-line contention (R7/R8 lesson: ~12ns/RMW
// serialized on one line => 1024 RMWs = +12us):
//   - per block: ONE relaxed atomic u64 STORE of packed {cnt,sum} (own addr)
//   - arrival: 2-level counters — 64 group counters (8 blocks each, private
//     128-B lines, parallel) -> 1 root counter (64 RMWs total)
//   - counters never reset: "last" detected by RMW return mod 8 / mod 64,
//     exactly one winner per replay for ANY initial value (poison-proof);
//     partials overwritten each replay => no memset node, graph = 1 node.
//   - ordering: store -> vmcnt(0) -> group RMW -> vmcnt(0) -> root RMW;
//     root-last block atomically loads all partials (performed-before chain),
//     reduces in FIXED order -> bit-deterministic output.

#define N 64
#define WPB 4                   // waves per 256-thread block
#define RPW 2                   // rows per wave
#define LN2 0.6931471805599453f
#define LOG2E 1.4426950408889634f

__device__ __forceinline__ float readlane_f(float v, int srclane) {
    return __int_as_float(__builtin_amdgcn_readlane(__float_as_int(v), srclane));
}

#define TERM(i, p, r) do {                                         \
    const int b_ = bb + (i);                                       \
    float t_  = readlane_f(pa2, b_) - pa2;                         \
    float g_  = __builtin_amdgcn_exp2f(-fabsf(t_));                \
    bool  m_  = b_ > e;                                            \
    float gm_ = m_ ? g_ : 0.0f;                                    \
    p = fmaf(gm_, p, p);              /* p *= (1 + masked g) */    \
    r += m_ ? fmaxf(t_, 0.0f) : 0.0f;                              \
} while (0)

__global__ __launch_bounds__(256) void rank_loss_fused(
    const float* __restrict__ logits, const int* __restrict__ kd,
    float* __restrict__ out,
    unsigned long long* __restrict__ partials,  // [nb] packed {cnt,sum}
    unsigned* __restrict__ gcnt,                // 64 counters, stride 32 u32
    unsigned* __restrict__ root,                // 1 counter
    int B, int nb)
{
    const int lane = threadIdx.x & 63;
    const int wave = threadIdx.x >> 6;

    __shared__ float ssum[WPB], scnt[WPB];
    __shared__ int finalizeFlag;
    if (threadIdx.x == 0) finalizeFlag = 0;

    float p0=1.f,p1=1.f,p2=1.f,p3=1.f,p4=1.f,p5=1.f,p6=1.f,p7=1.f;
    float r0=0.f,r1=0.f,r2=0.f,r3=0.f,r4=0.f,r5=0.f,r6=0.f,r7=0.f;
    float cnt = 0.f;

    #pragma unroll
    for (int rr = 0; rr < RPW; ++rr) {
        const int row = (blockIdx.x * WPB + wave) * RPW + rr;
        if (row < B) {
            const int base = row * N + lane;
            const int   k   = kd[base];
            const float pa2 = logits[base] * LOG2E;

            // group-end lane e: smallest j >= lane with (j==63 or k[j]!=k[j+1])
            const int knext = __shfl_down(k, 1);
            unsigned long long endm = __ballot(lane == 63 || k != knext);
            const int e = lane + __builtin_ctzll(endm >> lane);   // bit 63 set
            cnt += (float)(63 - e);

            #pragma unroll 1
            for (int bb = 0; bb < N; bb += 8) {
                TERM(0, p0, r0); TERM(1, p1, r1); TERM(2, p2, r2); TERM(3, p3, r3);
                TERM(4, p4, r4); TERM(5, p5, r5); TERM(6, p6, r6); TERM(7, p7, r7);
            }
        }
    }

    float prod = ((p0 * p1) * (p2 * p3)) * ((p4 * p5) * (p6 * p7));
    float rsum = ((r0 + r1) + (r2 + r3)) + ((r4 + r5) + (r6 + r7));
    float psum = rsum + __builtin_amdgcn_logf(prod);   // v_log_f32 == log2

    #pragma unroll
    for (int off = 32; off; off >>= 1) {
        psum += __shfl_down(psum, off);
        cnt  += __shfl_down(cnt,  off);
    }
    if (lane == 0) { ssum[wave] = psum; scnt[wave] = cnt; }
    __syncthreads();

    if (threadIdx.x == 0) {
        float s = 0.f, c = 0.f;
        #pragma unroll
        for (int w = 0; w < WPB; ++w) { s += ssum[w]; c += scnt[w]; }

        // publish this block's partial (single relaxed atomic store, own addr)
        unsigned long long pv =
            ((unsigned long long)__float_as_uint(c) << 32) |
            (unsigned long long)__float_as_uint(s);
        __hip_atomic_store(&partials[blockIdx.x], pv,
                           __ATOMIC_RELAXED, __HIP_MEMORY_SCOPE_AGENT);
        asm volatile("s_waitcnt vmcnt(0)" ::: "memory");

        // level-1 arrival: 8 blocks per group, private line per group
        const unsigned g = (unsigned)blockIdx.x >> 3;
        unsigned go = __hip_atomic_fetch_add(&gcnt[g * 32], 1u,
                           __ATOMIC_RELAXED, __HIP_MEMORY_SCOPE_AGENT);
        if ((go & 7u) == 7u) {                 // last of this group (any init)
            asm volatile("s_waitcnt vmcnt(0)" ::: "memory");
            // level-2 arrival: 64 group-winners -> root
            unsigned ro = __hip_atomic_fetch_add(root, 1u,
                               __ATOMIC_RELAXED, __HIP_MEMORY_SCOPE_AGENT);
            if ((ro & 63u) == 63u) {           // last overall (any init)
                asm volatile("s_waitcnt vmcnt(0)" ::: "memory");
                finalizeFlag = 1;
            }
        }
    }
    __syncthreads();

    if (finalizeFlag) {          // exactly one block per replay; fixed order
        const int t = threadIdx.x;
        float s = 0.f, c = 0.f;
        #pragma unroll
        for (int j = 0; j < 2; ++j) {          // nb = 512 = 2 * 256
            unsigned long long pv = __hip_atomic_load(&partials[j * 256 + t],
                               __ATOMIC_RELAXED, __HIP_MEMORY_SCOPE_AGENT);
            s += __uint_as_float((unsigned)(pv & 0xffffffffull));
            c += __uint_as_float((unsigned)(pv >> 32));
        }
        #pragma unroll
        for (int off = 32; off; off >>= 1) {
            s += __shfl_down(s, off);
            c += __shfl_down(c, off);
        }
        __shared__ float fs[WPB], fc[WPB];
        if (lane == 0) { fs[wave] = s; fc[wave] = c; }
        __syncthreads();
        if (t == 0) {
            float S = 0.f, C = 0.f;
            #pragma unroll
            for (int w = 0; w < WPB; ++w) { S += fs[w]; C += fc[w]; }
            out[0] = S * LN2 / C;
        }
    }
}

extern "C" void kernel_launch(void* const* d_in, const int* in_sizes, int n_in,
                              void* d_out, int out_size, void* d_ws, size_t ws_size,
                              hipStream_t stream) {
    const float* logits = (const float*)d_in[0];
    const int*   kd     = (const int*)d_in[1];
    float*       out    = (float*)d_out;
    const int B  = in_sizes[1] / N;                  // 4096
    const int nb = B / (WPB * RPW);                  // 512 blocks

    unsigned long long* partials = (unsigned long long*)d_ws;          // 4 KiB
    unsigned* gcnt = (unsigned*)((char*)d_ws + 8192);   // 64 x 128 B = 8 KiB
    unsigned* root = (unsigned*)((char*)d_ws + 20480);  // own line

    rank_loss_fused<<<nb, 256, 0, stream>>>(logits, kd, out, partials,
                                            gcnt, root, B, nb);
}

// Round 10
// 12.221 us; speedup vs baseline: 2.2665x; 1.0760x over previous
//
#include <hip/hip_runtime.h>
#include <math.h>

// Reranker tie-aware RankNet loss — R10 (unordered-pair rotation).
// B=4096 rows, n=64. 256 blocks x 512 thr; 8 waves/block, 2 rows/wave.
//
// Pair coverage: for d=1..32, lane a handles unordered pair {a, b=(a+d)&63}
// (d=32 restricted to lanes<32 — its mirror would duplicate). Each unordered
// pair appears exactly once. Direction from OWN lane's group bounds [s,e]
// (start index s, end index e; start array is non-decreasing):
//   m1 = b>e  -> start(a)<start(b): ordered pair (a,b), term softplus(pb-pa)
//   m2 = b<s  -> start(b)<start(a): ordered pair (b,a), term softplus(pa-pb)
// Both directions share factor (1 + 2^-|t|), t = pb-pa, and
//   max(-t,0) = max(t,0) - t  =>  relu part = [m1|m2]*max(t,0) - [m2]*t.
// => ONE v_exp_f32 per unordered pair (32 slots vs 64), one v_log per lane.
// Product chains: 64 factors/lane over 8 chains -> <= 2^8 each, no overflow.
// cnt analytic: sum over rows of (63 - e)  (== ref mask count).
//
// Finalize (R9-validated, contention-free): per block one relaxed u64 store
// of packed {cnt,sum}; 2-level arrival counters (32 groups of 8 on private
// 128-B lines -> root, 32 RMWs); counters never reset (mod-8/mod-32 winner
// detection is poison-proof); store -> vmcnt(0) -> RMW ordering chain; the
// winner block loads all partials and reduces in FIXED order.

#define N 64
#define WAVES 8                 // waves per 512-thread block
#define RPW 2                   // rows per wave
#define LN2 0.6931471805599453f
#define LOG2E 1.4426950408889634f

__global__ __launch_bounds__(512) void rank_loss_fused(
    const float* __restrict__ logits, const int* __restrict__ kd,
    float* __restrict__ out,
    unsigned long long* __restrict__ partials,  // [nb] packed {cnt,sum}
    unsigned* __restrict__ gcnt,                // 32 counters, stride 32 u32
    unsigned* __restrict__ root,                // 1 counter
    int B, int nb)
{
    const int lane = threadIdx.x & 63;
    const int wave = threadIdx.x >> 6;

    __shared__ float ssum[WAVES], scnt[WAVES];
    __shared__ int finalizeFlag;
    if (threadIdx.x == 0) finalizeFlag = 0;

    // 8 product chains; 4+4 relu accumulator chains
    float p0=1.f,p1=1.f,p2=1.f,p3=1.f,p4=1.f,p5=1.f,p6=1.f,p7=1.f;
    float rm0=0.f,rm1=0.f,rm2=0.f,rm3=0.f;     // sum of [m1|m2]*max(t,0)
    float rt0=0.f,rt1=0.f,rt2=0.f,rt3=0.f;     // sum of [m2]*t
    float cnt = 0.f;

    #pragma unroll
    for (int rr = 0; rr < RPW; ++rr) {
        const int row = (blockIdx.x * WAVES + wave) * RPW + rr;
        if (row < B) {
            const int base = row * N + lane;
            const int   k   = kd[base];
            const float pa  = logits[base] * LOG2E;

            const int kprev = __shfl_up(k, 1);
            const int knext = __shfl_down(k, 1);
            const unsigned long long endm   = __ballot(lane == 63 || k != knext);
            const unsigned long long startm = __ballot(lane == 0  || k != kprev);
            const int e = lane + __builtin_ctzll(endm >> lane);        // bit63 set
            const int s = lane - __builtin_clzll(startm << (63 - lane)); // bit0 set
            cnt += (float)(63 - e);

            #pragma unroll 32
            for (int d = 1; d <= 32; ++d) {
                const int b  = (lane + d) & 63;
                const float pb = __shfl(pa, b);
                const float t  = pb - pa;
                const float g  = __builtin_amdgcn_exp2f(-fabsf(t));
                const bool live = (d < 32) | (lane < 32);   // d folds when unrolled
                const bool m1 = (b > e) & live;
                const bool m2 = (b < s) & live;
                const bool mne = m1 | m2;
                const float gm = mne ? g : 0.0f;
                const float mx = mne ? fmaxf(t, 0.0f) : 0.0f;
                const float tm = m2 ? t : 0.0f;
                switch (d & 7) {   // literal when unrolled
                    case 0: p0 = fmaf(gm, p0, p0); break;
                    case 1: p1 = fmaf(gm, p1, p1); break;
                    case 2: p2 = fmaf(gm, p2, p2); break;
                    case 3: p3 = fmaf(gm, p3, p3); break;
                    case 4: p4 = fmaf(gm, p4, p4); break;
                    case 5: p5 = fmaf(gm, p5, p5); break;
                    case 6: p6 = fmaf(gm, p6, p6); break;
                    default: p7 = fmaf(gm, p7, p7); break;
                }
                switch (d & 3) {
                    case 0: rm0 += mx; rt0 += tm; break;
                    case 1: rm1 += mx; rt1 += tm; break;
                    case 2: rm2 += mx; rt2 += tm; break;
                    default: rm3 += mx; rt3 += tm; break;
                }
            }
        }
    }

    float prod = ((p0 * p1) * (p2 * p3)) * ((p4 * p5) * (p6 * p7));
    float rsum = ((rm0 + rm1) + (rm2 + rm3)) - ((rt0 + rt1) + (rt2 + rt3));
    float psum = rsum + __builtin_amdgcn_logf(prod);   // v_log_f32 == log2

    #pragma unroll
    for (int off = 32; off; off >>= 1) {
        psum += __shfl_down(psum, off);
        cnt  += __shfl_down(cnt,  off);
    }
    if (lane == 0) { ssum[wave] = psum; scnt[wave] = cnt; }
    __syncthreads();

    if (threadIdx.x == 0) {
        float sv = 0.f, cv = 0.f;
        #pragma unroll
        for (int w = 0; w < WAVES; ++w) { sv += ssum[w]; cv += scnt[w]; }

        unsigned long long pv =
            ((unsigned long long)__float_as_uint(cv) << 32) |
            (unsigned long long)__float_as_uint(sv);
        __hip_atomic_store(&partials[blockIdx.x], pv,
                           __ATOMIC_RELAXED, __HIP_MEMORY_SCOPE_AGENT);
        asm volatile("s_waitcnt vmcnt(0)" ::: "memory");

        const unsigned g = (unsigned)blockIdx.x >> 3;     // 32 groups of 8
        unsigned go = __hip_atomic_fetch_add(&gcnt[g * 32], 1u,
                           __ATOMIC_RELAXED, __HIP_MEMORY_SCOPE_AGENT);
        if ((go & 7u) == 7u) {
            asm volatile("s_waitcnt vmcnt(0)" ::: "memory");
            unsigned ro = __hip_atomic_fetch_add(root, 1u,
                               __ATOMIC_RELAXED, __HIP_MEMORY_SCOPE_AGENT);
            if ((ro & 31u) == 31u) {                      // 32 winners/replay
                asm volatile("s_waitcnt vmcnt(0)" ::: "memory");
                finalizeFlag = 1;
            }
        }
    }
    __syncthreads();

    if (finalizeFlag) {          // exactly one block per replay; fixed order
        const int t = threadIdx.x;
        float sv = 0.f, cv = 0.f;
        if (t < 256) {                          // nb = 256, one partial/thread
            unsigned long long pv = __hip_atomic_load(&partials[t],
                               __ATOMIC_RELAXED, __HIP_MEMORY_SCOPE_AGENT);
            sv = __uint_as_float((unsigned)(pv & 0xffffffffull));
            cv = __uint_as_float((unsigned)(pv >> 32));
        }
        #pragma unroll
        for (int off = 32; off; off >>= 1) {
            sv += __shfl_down(sv, off);
            cv += __shfl_down(cv, off);
        }
        __shared__ float fs[WAVES], fc[WAVES];
        if (lane == 0) { fs[wave] = sv; fc[wave] = cv; }
        __syncthreads();
        if (t == 0) {
            float S = 0.f, C = 0.f;
            #pragma unroll
            for (int w = 0; w < WAVES; ++w) { S += fs[w]; C += fc[w]; }
            out[0] = S * LN2 / C;
        }
    }
}

extern "C" void kernel_launch(void* const* d_in, const int* in_sizes, int n_in,
                              void* d_out, int out_size, void* d_ws, size_t ws_size,
                              hipStream_t stream) {
    const float* logits = (const float*)d_in[0];
    const int*   kd     = (const int*)d_in[1];
    float*       out    = (float*)d_out;
    const int B  = in_sizes[1] / N;                  // 4096
    const int nb = B / (WAVES * RPW);                // 256 blocks

    unsigned long long* partials = (unsigned long long*)d_ws;          // 2 KiB
    unsigned* gcnt = (unsigned*)((char*)d_ws + 8192);   // 32 x 128 B lines
    unsigned* root = (unsigned*)((char*)d_ws + 16384);  // own line

    rank_loss_fused<<<nb, WAVES * 64, 0, stream>>>(logits, kd, out, partials,
                                                   gcnt, root, B, nb);
}